// Round 2
// baseline (237.384 us; speedup 1.0000x reference)
//
#include <hip/hip_runtime.h>
#include <stdint.h>

#define A_NUM 9
#define H_FM 50
#define W_FM 80
#define N_ANCH (A_NUM * H_FM * W_FM)   // 36000
#define NSORT 65536
#define PRE_NMS_N 6000
#define POST_NMS_N 300
#define NMS_TH 0.7f
#define MASK_W 94            // ceil(6000/64)
#define MASK_STRIDE 96

typedef unsigned long long ull;

// base anchor widths/heights (verified vs generate_anchors with np.round half-to-even)
__constant__ float c_aw[9] = {184.f,368.f,736.f,128.f,256.f,512.f, 88.f,176.f,352.f};
__constant__ float c_ah[9] = { 96.f,192.f,384.f,128.f,256.f,512.f,176.f,352.f,704.f};

__device__ float4 g_boxes[N_ANCH];
__device__ ull    g_keys[NSORT];
__device__ float4 g_props[PRE_NMS_N];
__device__ ull    g_mask[(size_t)PRE_NMS_N * MASK_STRIDE];
__device__ ull    g_dead[MASK_STRIDE];
__device__ ull    g_rowany[MASK_STRIDE];
__device__ int    g_kept_idx[POST_NMS_N];
__device__ int    g_kept_count;

// ---------------- decode + key build ----------------
__global__ void k_decode(const float* __restrict__ scores,
                         const float* __restrict__ deltas,
                         const float* __restrict__ iminfo) {
    int i = blockIdx.x * blockDim.x + threadIdx.x;
    if (i < MASK_STRIDE) { g_dead[i] = 0ULL; g_rowany[i] = 0ULL; }
    if (i >= NSORT) return;
    if (i >= N_ANCH) { g_keys[i] = ~0ULL; return; }

    int a    = i % A_NUM;
    int cell = i / A_NUM;
    int x    = cell % W_FM;
    int y    = cell / W_FM;
    const int hw = H_FM * W_FM;

    float sc = scores[(A_NUM + a) * hw + cell];

    int dbase = (a * 4) * hw + cell;
    float d0 = deltas[dbase];
    float d1 = deltas[dbase + hw];
    float d2 = deltas[dbase + 2 * hw];
    float d3 = deltas[dbase + 3 * hw];
    d2 = fminf(fmaxf(d2, -10.f), 10.f);
    d3 = fminf(fmaxf(d3, -10.f), 10.f);

    float aw = c_aw[a], ah = c_ah[a];
    float acx = (float)(x * 16 + 8);
    float acy = (float)(y * 16 + 8);

    float pcx = d0 * aw + acx;
    float pcy = d1 * ah + acy;
    float pw  = expf(d2) * aw;
    float ph  = expf(d3) * ah;

    float x1 = pcx - 0.5f * pw;
    float y1 = pcy - 0.5f * ph;
    float x2 = pcx + 0.5f * pw;
    float y2 = pcy + 0.5f * ph;

    float imh = iminfo[0], imw = iminfo[1], ims = iminfo[2];
    x1 = fminf(fmaxf(x1, 0.f), imw - 1.f);
    y1 = fminf(fmaxf(y1, 0.f), imh - 1.f);
    x2 = fminf(fmaxf(x2, 0.f), imw - 1.f);
    y2 = fminf(fmaxf(y2, 0.f), imh - 1.f);

    float wsz = x2 - x1 + 1.f;
    float hsz = y2 - y1 + 1.f;
    float minsz = 16.f * ims;
    bool valid = (wsz >= minsz) && (hsz >= minsz);

    g_boxes[i] = make_float4(x1, y1, x2, y2);

    unsigned int u   = __float_as_uint(sc);
    unsigned int asc = (u & 0x80000000u) ? ~u : (u | 0x80000000u);
    unsigned int dk  = ~asc;                 // ascending dk == descending score
    if (!valid) dk = 0xFF800000u;            // == key of -inf score
    g_keys[i] = ((ull)dk << 32) | (unsigned int)i;
}

// ---------------- bitonic sort: local full sort of 2048-chunks ----------------
__global__ __launch_bounds__(1024) void k_sort_local() {
    __shared__ ull s[2048];
    int t = threadIdx.x;
    int base = blockIdx.x * 2048;
    s[t]        = g_keys[base + t];
    s[t + 1024] = g_keys[base + t + 1024];
    __syncthreads();
    for (int k = 2; k <= 2048; k <<= 1) {
        for (int j = k >> 1; j >= 1; j >>= 1) {
            int i = ((t & ~(j - 1)) << 1) | (t & (j - 1));
            int p = i | j;
            bool up = (((base + i) & k) == 0);
            ull a = s[i], b = s[p];
            if ((a > b) == up) { s[i] = b; s[p] = a; }
            __syncthreads();
        }
    }
    g_keys[base + t]        = s[t];
    g_keys[base + t + 1024] = s[t + 1024];
}

// ---------------- bitonic sort: strided (column) substages j>=2048 ----------------
template <int K>
__global__ void k_merge_col() {
    int g = blockIdx.x * blockDim.x + threadIdx.x;   // 0..2047
    ull v[32];
#pragma unroll
    for (int m = 0; m < 32; ++m) v[m] = g_keys[g + (m << 11)];
#pragma unroll
    for (int j = K >> 1; j >= 2048; j >>= 1) {
        const int jj = j >> 11;
#pragma unroll
        for (int m = 0; m < 32; ++m) {
            if ((m & jj) == 0) {
                const int p = m | jj;
                bool up = (((m << 11) & K) == 0);
                ull a = v[m], b = v[p];
                if ((a > b) == up) { v[m] = b; v[p] = a; }
            }
        }
    }
#pragma unroll
    for (int m = 0; m < 32; ++m) g_keys[g + (m << 11)] = v[m];
}

// ---------------- bitonic sort: local merge substages j<=1024 for stage k ----------------
__global__ __launch_bounds__(1024) void k_merge_local(int k) {
    __shared__ ull s[2048];
    int t = threadIdx.x;
    int base = blockIdx.x * 2048;
    s[t]        = g_keys[base + t];
    s[t + 1024] = g_keys[base + t + 1024];
    __syncthreads();
    for (int j = 1024; j >= 1; j >>= 1) {
        int i = ((t & ~(j - 1)) << 1) | (t & (j - 1));
        int p = i | j;
        bool up = (((base + i) & k) == 0);
        ull a = s[i], b = s[p];
        if ((a > b) == up) { s[i] = b; s[p] = a; }
        __syncthreads();
    }
    g_keys[base + t]        = s[t];
    g_keys[base + t + 1024] = s[t + 1024];
}

// ---------------- gather props + initial dead mask ----------------
__global__ void k_prep() {
    int r = blockIdx.x * blockDim.x + threadIdx.x;
    if (r >= PRE_NMS_N) return;
    ull key = g_keys[r];
    unsigned int dk = (unsigned int)(key >> 32);
    if (dk < 0xFF800000u) {                      // finite score (not -inf, not pad)
        unsigned int idx = (unsigned int)key;
        g_props[r] = g_boxes[idx];
    } else {
        g_props[r] = make_float4(0.f, 0.f, 0.f, 0.f);
        atomicOr(&g_dead[r >> 6], 1ULL << (r & 63));
    }
}

// ---------------- IoU suppression mask matrix + rowAny summary ----------------
__global__ void k_mask() {
    __shared__ float4 sj[256];
    int tid = threadIdx.x;
    int jbase = blockIdx.x * 256;
    int jj = jbase + tid;
    sj[tid] = (jj < PRE_NMS_N) ? g_props[jj] : make_float4(0.f, 0.f, 0.f, 0.f);
    __syncthreads();

    int li = tid & 63;
    int wl = tid >> 6;                       // 0..3
    int i  = blockIdx.y * 64 + li;
    int w  = blockIdx.x * 4 + wl;
    if (i >= PRE_NMS_N || w >= MASK_W) return;

    float4 bi = g_props[i];
    float ai = (bi.z - bi.x + 1.f) * (bi.w - bi.y + 1.f);
    ull bits = 0;
    int jstart = w * 64;
    int lbase = jstart - jbase;              // 0,64,128,192
    for (int b = 0; b < 64; ++b) {
        int j = jstart + b;
        if (j <= i || j >= PRE_NMS_N) continue;
        float4 bj = sj[lbase + b];
        float aj = (bj.z - bj.x + 1.f) * (bj.w - bj.y + 1.f);
        float iw = fminf(bi.z, bj.z) - fmaxf(bi.x, bj.x) + 1.f;
        float ih = fminf(bi.w, bj.w) - fmaxf(bi.y, bj.y) + 1.f;
        iw = fmaxf(iw, 0.f);
        ih = fmaxf(ih, 0.f);
        float inter = iw * ih;
        float iou = inter / (ai + aj - inter);
        if (iou > NMS_TH) bits |= (1ULL << b);
    }
    g_mask[(size_t)i * MASK_STRIDE + w] = bits;
    if (bits) atomicOr(&g_rowany[i >> 6], 1ULL << (i & 63));
}

// ---------------- sequential greedy scan (1 wave) ----------------
// rm = "processed or suppressed" bits. First alive = first zero bit.
// Kept boxes mark their own bit processed, so first-zero is always the frontier.
__device__ __forceinline__ int find_first_alive(ull rm0, ull rm1) {
    ull b0 = __ballot(~rm0 != 0ULL);
    if (b0) {
        int w = __ffsll(b0) - 1;
        ull word = __shfl(rm0, w);
        return w * 64 + (__ffsll(~word) - 1);
    }
    ull b1 = __ballot(~rm1 != 0ULL);
    if (b1) {
        int w = __ffsll(b1) - 1;
        ull word = __shfl(rm1, w);
        return (64 + w) * 64 + (__ffsll(~word) - 1);
    }
    return -1;
}

__global__ void k_scan() {
    int lane = threadIdx.x;
    ull rm0 = g_dead[lane];                               // words 0..63
    ull rm1 = (lane < MASK_W - 64) ? g_dead[64 + lane] : ~0ULL;  // words 64..93
    if (lane == 29) rm1 |= 0xFFFF000000000000ULL;         // pad indices 6000..6015
    ull ra0 = g_rowany[lane];
    ull ra1 = (lane < MASK_W - 64) ? g_rowany[64 + lane] : 0ULL;

    int kc = 0;
    int i = find_first_alive(rm0, rm1);
    while (i >= 0 && kc < POST_NMS_N) {
        if (lane == 0) g_kept_idx[kc] = i;
        kc++;
        int w = i >> 6, b = i & 63;
        if (w < 64) { if (lane == w)      rm0 |= 1ULL << b; }
        else        { if (lane == w - 64) rm1 |= 1ULL << b; }

        ull raw = (w < 64) ? __shfl(ra0, w) : __shfl(ra1, w - 64);
        if ((raw >> b) & 1ULL) {
            // this box suppresses someone: load its row, overlap with speculation
            const ull* __restrict__ row = g_mask + (size_t)i * MASK_STRIDE;
            ull d0 = row[lane];
            ull d1 = (lane < MASK_W - 64) ? row[64 + lane] : 0ULL;
            int i2 = find_first_alive(rm0, rm1);   // speculative next (pre-OR)
            rm0 |= d0;
            rm1 |= d1;
            if (i2 >= 0) {
                int w2 = i2 >> 6, b2 = i2 & 63;
                ull word2 = (w2 < 64) ? __shfl(rm0, w2) : __shfl(rm1, w2 - 64);
                if (((word2 >> b2) & 1ULL) == 0ULL) { i = i2; continue; }
            }
            i = find_first_alive(rm0, rm1);
        } else {
            i = find_first_alive(rm0, rm1);
        }
    }
    if (lane == 0) g_kept_count = kc;
}

// ---------------- write output ----------------
__global__ void k_out(float* __restrict__ out) {
    int r = blockIdx.x * blockDim.x + threadIdx.x;
    if (r >= POST_NMS_N) return;
    int kc = g_kept_count;
    float4 p = make_float4(0.f, 0.f, 0.f, 0.f);
    if (r < kc) p = g_props[g_kept_idx[r]];
    out[r * 5 + 0] = 0.f;
    out[r * 5 + 1] = p.x;
    out[r * 5 + 2] = p.y;
    out[r * 5 + 3] = p.z;
    out[r * 5 + 4] = p.w;
}

extern "C" void kernel_launch(void* const* d_in, const int* in_sizes, int n_in,
                              void* d_out, int out_size, void* d_ws, size_t ws_size,
                              hipStream_t stream) {
    const float* scores = (const float*)d_in[0];
    const float* deltas = (const float*)d_in[1];
    const float* iminfo = (const float*)d_in[2];
    float* out = (float*)d_out;

    k_decode<<<NSORT / 256, 256, 0, stream>>>(scores, deltas, iminfo);

    k_sort_local<<<32, 1024, 0, stream>>>();
    k_merge_col<4096><<<8, 256, 0, stream>>>();
    k_merge_local<<<32, 1024, 0, stream>>>(4096);
    k_merge_col<8192><<<8, 256, 0, stream>>>();
    k_merge_local<<<32, 1024, 0, stream>>>(8192);
    k_merge_col<16384><<<8, 256, 0, stream>>>();
    k_merge_local<<<32, 1024, 0, stream>>>(16384);
    k_merge_col<32768><<<8, 256, 0, stream>>>();
    k_merge_local<<<32, 1024, 0, stream>>>(32768);
    k_merge_col<65536><<<8, 256, 0, stream>>>();
    k_merge_local<<<32, 1024, 0, stream>>>(65536);

    k_prep<<<(PRE_NMS_N + 255) / 256, 256, 0, stream>>>();
    k_mask<<<dim3(24, 94), 256, 0, stream>>>();
    k_scan<<<1, 64, 0, stream>>>();
    k_out<<<2, 256, 0, stream>>>(out);
}

// Round 3
// 172.619 us; speedup vs baseline: 1.3752x; 1.3752x over previous
//
#include <hip/hip_runtime.h>
#include <stdint.h>

#define A_NUM 9
#define H_FM 50
#define W_FM 80
#define N_ANCH (A_NUM * H_FM * W_FM)   // 36000
#define NSORT 65536
#define PRE_NMS_N 6000
#define POST_NMS_N 300
#define NMS_TH 0.7f
#define MASK_W 94            // ceil(6000/64)
#define MASK_STRIDE 96

typedef unsigned long long ull;

// base anchor widths/heights (verified vs generate_anchors with np.round half-to-even)
__constant__ float c_aw[9] = {184.f,368.f,736.f,128.f,256.f,512.f, 88.f,176.f,352.f};
__constant__ float c_ah[9] = { 96.f,192.f,384.f,128.f,256.f,512.f,176.f,352.f,704.f};

__device__ float4 g_boxes[N_ANCH];
__device__ ull    g_keys[NSORT];
__device__ float4 g_props[PRE_NMS_N];
__device__ ull    g_mask[(size_t)PRE_NMS_N * MASK_STRIDE];
__device__ ull    g_colsup[MASK_W * 64];   // in-word column suppressor masks
__device__ ull    g_dead[MASK_STRIDE];
__device__ ull    g_rowany[MASK_STRIDE];
__device__ int    g_kept_idx[POST_NMS_N];
__device__ int    g_kept_count;

// ---------------- decode + key build ----------------
__global__ void k_decode(const float* __restrict__ scores,
                         const float* __restrict__ deltas,
                         const float* __restrict__ iminfo) {
    int i = blockIdx.x * blockDim.x + threadIdx.x;
    if (i < MASK_STRIDE) { g_dead[i] = 0ULL; g_rowany[i] = 0ULL; }
    if (i >= NSORT) return;
    if (i >= N_ANCH) { g_keys[i] = ~0ULL; return; }

    int a    = i % A_NUM;
    int cell = i / A_NUM;
    int x    = cell % W_FM;
    int y    = cell / W_FM;
    const int hw = H_FM * W_FM;

    float sc = scores[(A_NUM + a) * hw + cell];

    int dbase = (a * 4) * hw + cell;
    float d0 = deltas[dbase];
    float d1 = deltas[dbase + hw];
    float d2 = deltas[dbase + 2 * hw];
    float d3 = deltas[dbase + 3 * hw];
    d2 = fminf(fmaxf(d2, -10.f), 10.f);
    d3 = fminf(fmaxf(d3, -10.f), 10.f);

    float aw = c_aw[a], ah = c_ah[a];
    float acx = (float)(x * 16 + 8);
    float acy = (float)(y * 16 + 8);

    float pcx = d0 * aw + acx;
    float pcy = d1 * ah + acy;
    float pw  = expf(d2) * aw;
    float ph  = expf(d3) * ah;

    float x1 = pcx - 0.5f * pw;
    float y1 = pcy - 0.5f * ph;
    float x2 = pcx + 0.5f * pw;
    float y2 = pcy + 0.5f * ph;

    float imh = iminfo[0], imw = iminfo[1], ims = iminfo[2];
    x1 = fminf(fmaxf(x1, 0.f), imw - 1.f);
    y1 = fminf(fmaxf(y1, 0.f), imh - 1.f);
    x2 = fminf(fmaxf(x2, 0.f), imw - 1.f);
    y2 = fminf(fmaxf(y2, 0.f), imh - 1.f);

    float wsz = x2 - x1 + 1.f;
    float hsz = y2 - y1 + 1.f;
    float minsz = 16.f * ims;
    bool valid = (wsz >= minsz) && (hsz >= minsz);

    g_boxes[i] = make_float4(x1, y1, x2, y2);

    unsigned int u   = __float_as_uint(sc);
    unsigned int asc = (u & 0x80000000u) ? ~u : (u | 0x80000000u);
    unsigned int dk  = ~asc;                 // ascending dk == descending score
    if (!valid) dk = 0xFF800000u;            // == key of -inf score
    g_keys[i] = ((ull)dk << 32) | (unsigned int)i;
}

// ---------------- bitonic sort: local full sort of 2048-chunks ----------------
__global__ __launch_bounds__(1024) void k_sort_local() {
    __shared__ ull s[2048];
    int t = threadIdx.x;
    int base = blockIdx.x * 2048;
    s[t]        = g_keys[base + t];
    s[t + 1024] = g_keys[base + t + 1024];
    __syncthreads();
    for (int k = 2; k <= 2048; k <<= 1) {
        for (int j = k >> 1; j >= 1; j >>= 1) {
            int i = ((t & ~(j - 1)) << 1) | (t & (j - 1));
            int p = i | j;
            bool up = (((base + i) & k) == 0);
            ull a = s[i], b = s[p];
            if ((a > b) == up) { s[i] = b; s[p] = a; }
            __syncthreads();
        }
    }
    g_keys[base + t]        = s[t];
    g_keys[base + t + 1024] = s[t + 1024];
}

// ---------------- bitonic sort: strided (column) substages j>=2048 ----------------
template <int K>
__global__ void k_merge_col() {
    int g = blockIdx.x * blockDim.x + threadIdx.x;   // 0..2047
    ull v[32];
#pragma unroll
    for (int m = 0; m < 32; ++m) v[m] = g_keys[g + (m << 11)];
#pragma unroll
    for (int j = K >> 1; j >= 2048; j >>= 1) {
        const int jj = j >> 11;
#pragma unroll
        for (int m = 0; m < 32; ++m) {
            if ((m & jj) == 0) {
                const int p = m | jj;
                bool up = (((m << 11) & K) == 0);
                ull a = v[m], b = v[p];
                if ((a > b) == up) { v[m] = b; v[p] = a; }
            }
        }
    }
#pragma unroll
    for (int m = 0; m < 32; ++m) g_keys[g + (m << 11)] = v[m];
}

// ---------------- bitonic sort: local merge substages j<=1024 for stage k ----------------
__global__ __launch_bounds__(1024) void k_merge_local(int k) {
    __shared__ ull s[2048];
    int t = threadIdx.x;
    int base = blockIdx.x * 2048;
    s[t]        = g_keys[base + t];
    s[t + 1024] = g_keys[base + t + 1024];
    __syncthreads();
    for (int j = 1024; j >= 1; j >>= 1) {
        int i = ((t & ~(j - 1)) << 1) | (t & (j - 1));
        int p = i | j;
        bool up = (((base + i) & k) == 0);
        ull a = s[i], b = s[p];
        if ((a > b) == up) { s[i] = b; s[p] = a; }
        __syncthreads();
    }
    g_keys[base + t]        = s[t];
    g_keys[base + t + 1024] = s[t + 1024];
}

// ---------------- gather props + initial dead mask ----------------
__global__ void k_prep() {
    int r = blockIdx.x * blockDim.x + threadIdx.x;
    if (r >= PRE_NMS_N) return;
    ull key = g_keys[r];
    unsigned int dk = (unsigned int)(key >> 32);
    if (dk < 0xFF800000u) {                      // finite score (not -inf, not pad)
        unsigned int idx = (unsigned int)key;
        g_props[r] = g_boxes[idx];
    } else {
        g_props[r] = make_float4(0.f, 0.f, 0.f, 0.f);
        atomicOr(&g_dead[r >> 6], 1ULL << (r & 63));
    }
}

// ---------------- IoU suppression mask matrix + rowAny summary ----------------
__global__ void k_mask() {
    __shared__ float4 sj[256];
    int tid = threadIdx.x;
    int jbase = blockIdx.x * 256;
    int jj = jbase + tid;
    sj[tid] = (jj < PRE_NMS_N) ? g_props[jj] : make_float4(0.f, 0.f, 0.f, 0.f);
    __syncthreads();

    int li = tid & 63;
    int wl = tid >> 6;                       // 0..3
    int i  = blockIdx.y * 64 + li;
    int w  = blockIdx.x * 4 + wl;
    if (i >= PRE_NMS_N || w >= MASK_W) return;

    float4 bi = g_props[i];
    float ai = (bi.z - bi.x + 1.f) * (bi.w - bi.y + 1.f);
    ull bits = 0;
    int jstart = w * 64;
    int lbase = jstart - jbase;              // 0,64,128,192
    for (int b = 0; b < 64; ++b) {
        int j = jstart + b;
        if (j <= i || j >= PRE_NMS_N) continue;
        float4 bj = sj[lbase + b];
        float aj = (bj.z - bj.x + 1.f) * (bj.w - bj.y + 1.f);
        float iw = fminf(bi.z, bj.z) - fmaxf(bi.x, bj.x) + 1.f;
        float ih = fminf(bi.w, bj.w) - fmaxf(bi.y, bj.y) + 1.f;
        iw = fmaxf(iw, 0.f);
        ih = fmaxf(ih, 0.f);
        float inter = iw * ih;
        float iou = inter / (ai + aj - inter);
        if (iou > NMS_TH) bits |= (1ULL << b);
    }
    g_mask[(size_t)i * MASK_STRIDE + w] = bits;
    if (bits) atomicOr(&g_rowany[i >> 6], 1ULL << (i & 63));
}

// ---------------- in-word column suppressor masks ----------------
// colsup[j] bit b = (b < j&63) && IoU(box_{w*64+b}, box_j) > th
__global__ void k_colsup() {
    __shared__ float4 sb[64];
    int w = blockIdx.x;      // 0..93
    int j = threadIdx.x;     // 0..63
    int gj = w * 64 + j;
    float4 bj = (gj < PRE_NMS_N) ? g_props[gj] : make_float4(0.f, 0.f, 0.f, 0.f);
    sb[j] = bj;
    __syncthreads();
    float aj = (bj.z - bj.x + 1.f) * (bj.w - bj.y + 1.f);
    ull bits = 0;
    for (int b = 0; b < j; ++b) {
        float4 bi = sb[b];
        float ai = (bi.z - bi.x + 1.f) * (bi.w - bi.y + 1.f);
        float iw = fminf(bi.z, bj.z) - fmaxf(bi.x, bj.x) + 1.f;
        float ih = fminf(bi.w, bj.w) - fmaxf(bi.y, bj.y) + 1.f;
        iw = fmaxf(iw, 0.f);
        ih = fmaxf(ih, 0.f);
        float inter = iw * ih;
        float iou = inter / (ai + aj - inter);
        if (iou > NMS_TH) bits |= (1ULL << b);
    }
    g_colsup[gj] = bits;
}

// ---------------- word-serial ballot-based greedy scan (1 wave) ----------------
// Per 64-box word: fixed-point resolution with ballots (no shfl in the hot chain).
// U = undecided alive, K = kept. A box with no suppressor in U|K is kept;
// a box with a suppressor in K is dead. Converges >=1 box/round.
__global__ void k_scan() {
    int lane = threadIdx.x;
    ull rm0 = g_dead[lane];                                // words 0..63
    ull rm1 = (lane < MASK_W - 64) ? g_dead[64 + lane] : ~0ULL;  // words 64..93
    if (lane == 29) rm1 |= 0xFFFF000000000000ULL;          // pad indices 6000..6015
    ull ra0 = g_rowany[lane];
    ull ra1 = (lane < MASK_W - 64) ? g_rowany[64 + lane] : 0ULL;

    int kc = 0;
    ull diag = g_colsup[lane];                             // word 0 prefetch
    for (int w = 0; w < MASK_W; ++w) {
        ull diag_next = (w + 1 < MASK_W) ? g_colsup[(w + 1) * 64 + lane] : 0ULL;
        ull curw = (w < 64) ? __shfl(rm0, w) : __shfl(rm1, w - 64);
        ull raw  = (w < 64) ? __shfl(ra0, w) : __shfl(ra1, w - 64);

        ull U = ~curw;
        ull K = 0;
        while (U) {
            ull UK = U | K;
            bool deadp = (diag & K)  != 0ULL;
            bool freep = (diag & UK) == 0ULL;
            ull newdead = __ballot(deadp) & U;
            U &= ~newdead;
            ull newkept = __ballot(freep) & U;
            U &= ~newkept;
            K |= newkept;
            if (!newkept && !newdead) break;   // safety; cannot happen
        }

        int cnt  = __popcll(K);
        int take = min(cnt, POST_NMS_N - kc);
        if (K & (1ULL << lane)) {
            int pos = kc + __popcll(K & ((1ULL << lane) - 1ULL));
            if (pos < POST_NMS_N) g_kept_idx[pos] = w * 64 + lane;
        }
        kc += take;
        if (kc >= POST_NMS_N) break;

        ull need = K & raw;                    // only rows that suppress someone
        while (need) {
            int f = __ffsll(need) - 1;
            need &= need - 1;
            const ull* __restrict__ row = g_mask + (size_t)(w * 64 + f) * MASK_STRIDE;
            rm0 |= row[lane];
            if (lane < MASK_W - 64) rm1 |= row[64 + lane];
        }
        diag = diag_next;
    }
    if (lane == 0) g_kept_count = (kc < POST_NMS_N) ? kc : POST_NMS_N;
}

// ---------------- write output ----------------
__global__ void k_out(float* __restrict__ out) {
    int r = blockIdx.x * blockDim.x + threadIdx.x;
    if (r >= POST_NMS_N) return;
    int kc = g_kept_count;
    float4 p = make_float4(0.f, 0.f, 0.f, 0.f);
    if (r < kc) p = g_props[g_kept_idx[r]];
    out[r * 5 + 0] = 0.f;
    out[r * 5 + 1] = p.x;
    out[r * 5 + 2] = p.y;
    out[r * 5 + 3] = p.z;
    out[r * 5 + 4] = p.w;
}

extern "C" void kernel_launch(void* const* d_in, const int* in_sizes, int n_in,
                              void* d_out, int out_size, void* d_ws, size_t ws_size,
                              hipStream_t stream) {
    const float* scores = (const float*)d_in[0];
    const float* deltas = (const float*)d_in[1];
    const float* iminfo = (const float*)d_in[2];
    float* out = (float*)d_out;

    k_decode<<<NSORT / 256, 256, 0, stream>>>(scores, deltas, iminfo);

    k_sort_local<<<32, 1024, 0, stream>>>();
    k_merge_col<4096><<<8, 256, 0, stream>>>();
    k_merge_local<<<32, 1024, 0, stream>>>(4096);
    k_merge_col<8192><<<8, 256, 0, stream>>>();
    k_merge_local<<<32, 1024, 0, stream>>>(8192);
    k_merge_col<16384><<<8, 256, 0, stream>>>();
    k_merge_local<<<32, 1024, 0, stream>>>(16384);
    k_merge_col<32768><<<8, 256, 0, stream>>>();
    k_merge_local<<<32, 1024, 0, stream>>>(32768);
    k_merge_col<65536><<<8, 256, 0, stream>>>();
    k_merge_local<<<32, 1024, 0, stream>>>(65536);

    k_prep<<<(PRE_NMS_N + 255) / 256, 256, 0, stream>>>();
    k_mask<<<dim3(24, 94), 256, 0, stream>>>();
    k_colsup<<<MASK_W, 64, 0, stream>>>();
    k_scan<<<1, 64, 0, stream>>>();
    k_out<<<2, 256, 0, stream>>>(out);
}

// Round 4
// 171.245 us; speedup vs baseline: 1.3862x; 1.0080x over previous
//
#include <hip/hip_runtime.h>
#include <stdint.h>

#define A_NUM 9
#define H_FM 50
#define W_FM 80
#define N_ANCH (A_NUM * H_FM * W_FM)   // 36000
#define NSORT 65536
#define PRE_NMS_N 6000
#define POST_NMS_N 300
#define NMS_TH 0.7f
#define MASK_W 94            // ceil(6000/64)
#define MASK_STRIDE 96

typedef unsigned long long ull;

// base anchor widths/heights (verified vs generate_anchors with np.round half-to-even)
__constant__ float c_aw[9] = {184.f,368.f,736.f,128.f,256.f,512.f, 88.f,176.f,352.f};
__constant__ float c_ah[9] = { 96.f,192.f,384.f,128.f,256.f,512.f,176.f,352.f,704.f};

__device__ float4 g_boxes[N_ANCH];
__device__ ull    g_keys[NSORT];
__device__ float4 g_props[PRE_NMS_N];
__device__ ull    g_mask[(size_t)PRE_NMS_N * MASK_STRIDE];
__device__ ull    g_colsup[MASK_W * 64];   // in-word column suppressor masks
__device__ ull    g_dead[MASK_STRIDE];
__device__ ull    g_rowany[MASK_STRIDE];

// ---------------- decode + key build ----------------
__global__ void k_decode(const float* __restrict__ scores,
                         const float* __restrict__ deltas,
                         const float* __restrict__ iminfo) {
    int i = blockIdx.x * blockDim.x + threadIdx.x;
    if (i < MASK_STRIDE) { g_dead[i] = 0ULL; g_rowany[i] = 0ULL; }
    if (i >= NSORT) return;
    if (i >= N_ANCH) { g_keys[i] = ~0ULL; return; }

    int a    = i % A_NUM;
    int cell = i / A_NUM;
    int x    = cell % W_FM;
    int y    = cell / W_FM;
    const int hw = H_FM * W_FM;

    float sc = scores[(A_NUM + a) * hw + cell];

    int dbase = (a * 4) * hw + cell;
    float d0 = deltas[dbase];
    float d1 = deltas[dbase + hw];
    float d2 = deltas[dbase + 2 * hw];
    float d3 = deltas[dbase + 3 * hw];
    d2 = fminf(fmaxf(d2, -10.f), 10.f);
    d3 = fminf(fmaxf(d3, -10.f), 10.f);

    float aw = c_aw[a], ah = c_ah[a];
    float acx = (float)(x * 16 + 8);
    float acy = (float)(y * 16 + 8);

    float pcx = d0 * aw + acx;
    float pcy = d1 * ah + acy;
    float pw  = expf(d2) * aw;
    float ph  = expf(d3) * ah;

    float x1 = pcx - 0.5f * pw;
    float y1 = pcy - 0.5f * ph;
    float x2 = pcx + 0.5f * pw;
    float y2 = pcy + 0.5f * ph;

    float imh = iminfo[0], imw = iminfo[1], ims = iminfo[2];
    x1 = fminf(fmaxf(x1, 0.f), imw - 1.f);
    y1 = fminf(fmaxf(y1, 0.f), imh - 1.f);
    x2 = fminf(fmaxf(x2, 0.f), imw - 1.f);
    y2 = fminf(fmaxf(y2, 0.f), imh - 1.f);

    float wsz = x2 - x1 + 1.f;
    float hsz = y2 - y1 + 1.f;
    float minsz = 16.f * ims;
    bool valid = (wsz >= minsz) && (hsz >= minsz);

    g_boxes[i] = make_float4(x1, y1, x2, y2);

    unsigned int u   = __float_as_uint(sc);
    unsigned int asc = (u & 0x80000000u) ? ~u : (u | 0x80000000u);
    unsigned int dk  = ~asc;                 // ascending dk == descending score
    if (!valid) dk = 0xFF800000u;            // == key of -inf score
    g_keys[i] = ((ull)dk << 32) | (unsigned int)i;
}

// ---------------- bitonic sort: local full sort of 2048-chunks ----------------
__global__ __launch_bounds__(1024) void k_sort_local() {
    __shared__ ull s[2048];
    int t = threadIdx.x;
    int base = blockIdx.x * 2048;
    s[t]        = g_keys[base + t];
    s[t + 1024] = g_keys[base + t + 1024];
    __syncthreads();
    for (int k = 2; k <= 2048; k <<= 1) {
        for (int j = k >> 1; j >= 1; j >>= 1) {
            int i = ((t & ~(j - 1)) << 1) | (t & (j - 1));
            int p = i | j;
            bool up = (((base + i) & k) == 0);
            ull a = s[i], b = s[p];
            if ((a > b) == up) { s[i] = b; s[p] = a; }
            __syncthreads();
        }
    }
    g_keys[base + t]        = s[t];
    g_keys[base + t + 1024] = s[t + 1024];
}

// ---------------- bitonic sort: strided (column) substages j>=2048 ----------------
template <int K>
__global__ void k_merge_col() {
    int g = blockIdx.x * blockDim.x + threadIdx.x;   // 0..2047
    ull v[32];
#pragma unroll
    for (int m = 0; m < 32; ++m) v[m] = g_keys[g + (m << 11)];
#pragma unroll
    for (int j = K >> 1; j >= 2048; j >>= 1) {
        const int jj = j >> 11;
#pragma unroll
        for (int m = 0; m < 32; ++m) {
            if ((m & jj) == 0) {
                const int p = m | jj;
                bool up = (((m << 11) & K) == 0);
                ull a = v[m], b = v[p];
                if ((a > b) == up) { v[m] = b; v[p] = a; }
            }
        }
    }
#pragma unroll
    for (int m = 0; m < 32; ++m) g_keys[g + (m << 11)] = v[m];
}

// ---------------- bitonic sort: local merge substages j<=1024 for stage k ----------------
__global__ __launch_bounds__(1024) void k_merge_local(int k) {
    __shared__ ull s[2048];
    int t = threadIdx.x;
    int base = blockIdx.x * 2048;
    s[t]        = g_keys[base + t];
    s[t + 1024] = g_keys[base + t + 1024];
    __syncthreads();
    for (int j = 1024; j >= 1; j >>= 1) {
        int i = ((t & ~(j - 1)) << 1) | (t & (j - 1));
        int p = i | j;
        bool up = (((base + i) & k) == 0);
        ull a = s[i], b = s[p];
        if ((a > b) == up) { s[i] = b; s[p] = a; }
        __syncthreads();
    }
    g_keys[base + t]        = s[t];
    g_keys[base + t + 1024] = s[t + 1024];
}

// ---------------- gather props + initial dead mask ----------------
__global__ void k_prep() {
    int r = blockIdx.x * blockDim.x + threadIdx.x;
    if (r >= PRE_NMS_N) return;
    ull key = g_keys[r];
    unsigned int dk = (unsigned int)(key >> 32);
    if (dk < 0xFF800000u) {                      // finite score (not -inf, not pad)
        unsigned int idx = (unsigned int)key;
        g_props[r] = g_boxes[idx];
    } else {
        g_props[r] = make_float4(0.f, 0.f, 0.f, 0.f);
        atomicOr(&g_dead[r >> 6], 1ULL << (r & 63));
    }
}

// ---------------- IoU suppression mask matrix + rowAny summary ----------------
__global__ void k_mask() {
    __shared__ float4 sj[256];
    int tid = threadIdx.x;
    int jbase = blockIdx.x * 256;
    int jj = jbase + tid;
    sj[tid] = (jj < PRE_NMS_N) ? g_props[jj] : make_float4(0.f, 0.f, 0.f, 0.f);
    __syncthreads();

    int li = tid & 63;
    int wl = tid >> 6;                       // 0..3
    int i  = blockIdx.y * 64 + li;
    int w  = blockIdx.x * 4 + wl;
    if (i >= PRE_NMS_N || w >= MASK_W) return;

    float4 bi = g_props[i];
    float ai = (bi.z - bi.x + 1.f) * (bi.w - bi.y + 1.f);
    ull bits = 0;
    int jstart = w * 64;
    int lbase = jstart - jbase;              // 0,64,128,192
    for (int b = 0; b < 64; ++b) {
        int j = jstart + b;
        if (j <= i || j >= PRE_NMS_N) continue;
        float4 bj = sj[lbase + b];
        float aj = (bj.z - bj.x + 1.f) * (bj.w - bj.y + 1.f);
        float iw = fminf(bi.z, bj.z) - fmaxf(bi.x, bj.x) + 1.f;
        float ih = fminf(bi.w, bj.w) - fmaxf(bi.y, bj.y) + 1.f;
        iw = fmaxf(iw, 0.f);
        ih = fmaxf(ih, 0.f);
        float inter = iw * ih;
        float iou = inter / (ai + aj - inter);
        if (iou > NMS_TH) bits |= (1ULL << b);
    }
    g_mask[(size_t)i * MASK_STRIDE + w] = bits;
    if (bits) atomicOr(&g_rowany[i >> 6], 1ULL << (i & 63));
}

// ---------------- in-word column suppressor masks ----------------
__global__ void k_colsup() {
    __shared__ float4 sb[64];
    int w = blockIdx.x;      // 0..93
    int j = threadIdx.x;     // 0..63
    int gj = w * 64 + j;
    float4 bj = (gj < PRE_NMS_N) ? g_props[gj] : make_float4(0.f, 0.f, 0.f, 0.f);
    sb[j] = bj;
    __syncthreads();
    float aj = (bj.z - bj.x + 1.f) * (bj.w - bj.y + 1.f);
    ull bits = 0;
    for (int b = 0; b < j; ++b) {
        float4 bi = sb[b];
        float ai = (bi.z - bi.x + 1.f) * (bi.w - bi.y + 1.f);
        float iw = fminf(bi.z, bj.z) - fmaxf(bi.x, bj.x) + 1.f;
        float ih = fminf(bi.w, bj.w) - fmaxf(bi.y, bj.y) + 1.f;
        iw = fmaxf(iw, 0.f);
        ih = fmaxf(ih, 0.f);
        float inter = iw * ih;
        float iou = inter / (ai + aj - inter);
        if (iou > NMS_TH) bits |= (1ULL << b);
    }
    g_colsup[gj] = bits;
}

// ---------------- word-serial ballot scan + batched row-OR (16-deep MLP) ----------------
#define BATCH 16
__global__ void k_scan(float* __restrict__ out) {
    __shared__ int s_kept[POST_NMS_N];
    int lane = threadIdx.x;
    ull rm0 = g_dead[lane];                                // words 0..63
    ull rm1 = (lane < MASK_W - 64) ? g_dead[64 + lane] : ~0ULL;  // words 64..93
    if (lane == 29) rm1 |= 0xFFFF000000000000ULL;          // pad indices 6000..6015
    ull ra0 = g_rowany[lane];
    ull ra1 = (lane < MASK_W - 64) ? g_rowany[64 + lane] : 0ULL;

    int kc = 0;
    ull diag = g_colsup[lane];                             // word 0 prefetch
    for (int w = 0; w < MASK_W; ++w) {
        ull diag_next = (w + 1 < MASK_W) ? g_colsup[(w + 1) * 64 + lane] : 0ULL;
        ull curw = (w < 64) ? __shfl(rm0, w) : __shfl(rm1, w - 64);
        ull raw  = (w < 64) ? __shfl(ra0, w) : __shfl(ra1, w - 64);

        // intra-word greedy fixed-point via ballots
        ull U = ~curw;
        ull K = 0;
        while (U) {
            ull UK = U | K;
            bool deadp = (diag & K)  != 0ULL;
            bool freep = (diag & UK) == 0ULL;
            ull newdead = __ballot(deadp) & U;
            U &= ~newdead;
            ull newkept = __ballot(freep) & U;
            U &= ~newkept;
            K |= newkept;
            if (!newkept && !newdead) break;   // safety; cannot happen
        }

        int cnt  = __popcll(K);
        int take = min(cnt, POST_NMS_N - kc);
        if (K & (1ULL << lane)) {
            int pos = kc + __popcll(K & ((1ULL << lane) - 1ULL));
            if (pos < POST_NMS_N) s_kept[pos] = w * 64 + lane;
        }
        kc += take;
        if (kc >= POST_NMS_N) break;

        // batched parallel row-OR: all rows of this word's kept suppressors
        ull need = K & raw;
        while (need) {
            int id[BATCH];
            int n = 0;
#pragma unroll
            for (int t = 0; t < BATCH; ++t) {
                id[t] = 0;
                if (need) { id[t] = __ffsll(need) - 1; need &= need - 1; n = t + 1; }
            }
            ull a0 = 0, a1 = 0;
#pragma unroll
            for (int t = 0; t < BATCH; ++t) {
                const ull* __restrict__ row =
                    g_mask + (size_t)(w * 64 + id[t]) * MASK_STRIDE;
                ull m = (t < n) ? ~0ULL : 0ULL;
                a0 |= row[lane] & m;
                if (lane < MASK_W - 64) a1 |= row[64 + lane] & m;
            }
            rm0 |= a0;
            rm1 |= a1;
        }
        diag = diag_next;
    }

    int kcf = (kc < POST_NMS_N) ? kc : POST_NMS_N;
    __syncthreads();
    for (int r = lane; r < POST_NMS_N; r += 64) {
        float4 p = make_float4(0.f, 0.f, 0.f, 0.f);
        if (r < kcf) p = g_props[s_kept[r]];
        out[r * 5 + 0] = 0.f;
        out[r * 5 + 1] = p.x;
        out[r * 5 + 2] = p.y;
        out[r * 5 + 3] = p.z;
        out[r * 5 + 4] = p.w;
    }
}

extern "C" void kernel_launch(void* const* d_in, const int* in_sizes, int n_in,
                              void* d_out, int out_size, void* d_ws, size_t ws_size,
                              hipStream_t stream) {
    const float* scores = (const float*)d_in[0];
    const float* deltas = (const float*)d_in[1];
    const float* iminfo = (const float*)d_in[2];
    float* out = (float*)d_out;

    k_decode<<<NSORT / 256, 256, 0, stream>>>(scores, deltas, iminfo);

    k_sort_local<<<32, 1024, 0, stream>>>();
    k_merge_col<4096><<<8, 256, 0, stream>>>();
    k_merge_local<<<32, 1024, 0, stream>>>(4096);
    k_merge_col<8192><<<8, 256, 0, stream>>>();
    k_merge_local<<<32, 1024, 0, stream>>>(8192);
    k_merge_col<16384><<<8, 256, 0, stream>>>();
    k_merge_local<<<32, 1024, 0, stream>>>(16384);
    k_merge_col<32768><<<8, 256, 0, stream>>>();
    k_merge_local<<<32, 1024, 0, stream>>>(32768);
    k_merge_col<65536><<<8, 256, 0, stream>>>();
    k_merge_local<<<32, 1024, 0, stream>>>(65536);

    k_prep<<<(PRE_NMS_N + 255) / 256, 256, 0, stream>>>();
    k_mask<<<dim3(24, 94), 256, 0, stream>>>();
    k_colsup<<<MASK_W, 64, 0, stream>>>();
    k_scan<<<1, 64, 0, stream>>>(out);
}